// Round 1
// baseline (110.453 us; speedup 1.0000x reference)
//
#include <hip/hip_runtime.h>

// Y = 2*X elementwise over 8192x8192 fp32, with Y[0][1] = -2*X[0][1].
// Memory-bound streaming kernel: float4 vectorized, grid-stride.

__global__ __launch_bounds__(256) void scale2_kernel(const float4* __restrict__ in,
                                                     float4* __restrict__ out,
                                                     int n4) {
    int stride = gridDim.x * blockDim.x;
    for (int i = blockIdx.x * blockDim.x + threadIdx.x; i < n4; i += stride) {
        float4 v = in[i];
        v.x *= 2.0f;
        v.y *= 2.0f;
        v.z *= 2.0f;
        v.w *= 2.0f;
        if (i == 0) v.y = -v.y;   // flat element 1 == .y of vec 0
        out[i] = v;
    }
}

extern "C" void kernel_launch(void* const* d_in, const int* in_sizes, int n_in,
                              void* d_out, int out_size, void* d_ws, size_t ws_size,
                              hipStream_t stream) {
    const float4* in = (const float4*)d_in[0];
    float4* out = (float4*)d_out;
    int n = in_sizes[0];          // 8192*8192 = 67,108,864 (divisible by 4)
    int n4 = n / 4;               // 16,777,216 float4s

    const int block = 256;
    int grid = (n4 + block - 1) / block;
    if (grid > 2048) grid = 2048; // grid-stride the rest (G11)

    scale2_kernel<<<grid, block, 0, stream>>>(in, out, n4);
}

// Round 2
// 88.030 us; speedup vs baseline: 1.2547x; 1.2547x over previous
//
#include <hip/hip_runtime.h>

// Y = 2*X elementwise over 8192x8192 fp32, with Y[0][1] = -2*X[0][1].
// Memory-bound streaming kernel: float4 loads (cached, L3 may retain the
// 256 MiB input across graph replays) + non-temporal stores (output is
// write-once, keep it from evicting the input from Infinity Cache).
// Unroll-by-4 for memory-level parallelism.

typedef float f32x4 __attribute__((ext_vector_type(4)));

__global__ __launch_bounds__(256) void scale2_kernel(const f32x4* __restrict__ in,
                                                     f32x4* __restrict__ out,
                                                     int n4) {
    const int tid = blockIdx.x * blockDim.x + threadIdx.x;
    const int stride = gridDim.x * blockDim.x;

    int i = tid;
    // Main unrolled loop: 4 independent 16B loads in flight per wave.
    for (; i + 3 * stride < n4; i += 4 * stride) {
        f32x4 a = in[i];
        f32x4 b = in[i + stride];
        f32x4 c = in[i + 2 * stride];
        f32x4 d = in[i + 3 * stride];
        a *= 2.0f; b *= 2.0f; c *= 2.0f; d *= 2.0f;
        if (i == 0) a.y = -a.y;   // flat element 1 == .y of vec 0
        __builtin_nontemporal_store(a, &out[i]);
        __builtin_nontemporal_store(b, &out[i + stride]);
        __builtin_nontemporal_store(c, &out[i + 2 * stride]);
        __builtin_nontemporal_store(d, &out[i + 3 * stride]);
    }
    // Remainder (not taken for 8192^2, kept for safety).
    for (; i < n4; i += stride) {
        f32x4 v = in[i];
        v *= 2.0f;
        if (i == 0) v.y = -v.y;
        __builtin_nontemporal_store(v, &out[i]);
    }
}

extern "C" void kernel_launch(void* const* d_in, const int* in_sizes, int n_in,
                              void* d_out, int out_size, void* d_ws, size_t ws_size,
                              hipStream_t stream) {
    const f32x4* in = (const f32x4*)d_in[0];
    f32x4* out = (f32x4*)d_out;
    int n = in_sizes[0];          // 8192*8192 = 67,108,864 (divisible by 4)
    int n4 = n / 4;               // 16,777,216 float4s

    const int block = 256;
    int grid = (n4 + block - 1) / block;
    if (grid > 2048) grid = 2048; // grid-stride; 32 iters/thread, 8 blocks/CU

    scale2_kernel<<<grid, block, 0, stream>>>(in, out, n4);
}

// Round 3
// 81.371 us; speedup vs baseline: 1.3574x; 1.0818x over previous
//
#include <hip/hip_runtime.h>

// Y = 2*X elementwise over 8192x8192 fp32, with Y[0][1] = -2*X[0][1].
// Exact-cover streaming kernel: 8192 blocks x 256 threads, each thread
// processes 8 float4s (8 independent loads in flight -> max MLP), cached
// loads (let L2/L3 retain input across graph replays) + non-temporal
// stores (write-once output shouldn't evict the input).

typedef float f32x4 __attribute__((ext_vector_type(4)));

#define VPT 8  // float4s per thread

__global__ __launch_bounds__(256) void scale2_kernel(const f32x4* __restrict__ in,
                                                     f32x4* __restrict__ out) {
    // Block covers 256*VPT consecutive float4s; lane i handles base+i, base+i+256, ...
    const int base = blockIdx.x * (256 * VPT) + threadIdx.x;

    f32x4 v[VPT];
#pragma unroll
    for (int k = 0; k < VPT; ++k)
        v[k] = in[base + k * 256];        // 8 independent global_load_dwordx4

#pragma unroll
    for (int k = 0; k < VPT; ++k)
        v[k] *= 2.0f;

    if (base == 0) v[0].y = -v[0].y;      // flat element 1 == .y of vec 0

#pragma unroll
    for (int k = 0; k < VPT; ++k)
        __builtin_nontemporal_store(v[k], &out[base + k * 256]);
}

extern "C" void kernel_launch(void* const* d_in, const int* in_sizes, int n_in,
                              void* d_out, int out_size, void* d_ws, size_t ws_size,
                              hipStream_t stream) {
    const f32x4* in = (const f32x4*)d_in[0];
    f32x4* out = (f32x4*)d_out;
    int n = in_sizes[0];            // 8192*8192 = 67,108,864
    int n4 = n / 4;                 // 16,777,216 float4s
    int grid = n4 / (256 * VPT);    // 8192 blocks, exact cover (n4 % 2048 == 0)

    scale2_kernel<<<grid, 256, 0, stream>>>(in, out);
}